// Round 1
// baseline (436.089 us; speedup 1.0000x reference)
//
#include <hip/hip_runtime.h>
#include <math.h>

// DigitCaps2: B=128 batch, C=1024 in_caps, I=16 in_dim, N=16 num_caps, D=16 dim_caps
#define NB 128
#define NC 1024
#define NN 16
#define ND 16
#define NI 16
#define NCH 32            // c-chunks
#define CPC (NC / NCH)    // 32 c per chunk
#define COEF 0.25f        // 1/sqrt(16)

// dot of one W row (16 floats at wr) with x row held in x0..x3, accumulated into acc
__device__ __forceinline__ float dot16(const float4* __restrict__ wr,
                                       float4 x0, float4 x1, float4 x2, float4 x3,
                                       float acc) {
  float4 w0 = wr[0], w1 = wr[1], w2 = wr[2], w3 = wr[3];
  acc = fmaf(w0.x, x0.x, acc); acc = fmaf(w0.y, x0.y, acc);
  acc = fmaf(w0.z, x0.z, acc); acc = fmaf(w0.w, x0.w, acc);
  acc = fmaf(w1.x, x1.x, acc); acc = fmaf(w1.y, x1.y, acc);
  acc = fmaf(w1.z, x1.z, acc); acc = fmaf(w1.w, x1.w, acc);
  acc = fmaf(w2.x, x2.x, acc); acc = fmaf(w2.y, x2.y, acc);
  acc = fmaf(w2.z, x2.z, acc); acc = fmaf(w2.w, x2.w, acc);
  acc = fmaf(w3.x, x3.x, acc); acc = fmaf(w3.y, x3.y, acc);
  acc = fmaf(w3.z, x3.z, acc); acc = fmaf(w3.w, x3.w, acc);
  return acc;
}

// Pass 1: partial usum over c-chunks. part[n][ch][b][d]
__global__ __launch_bounds__(256) void k_usum(const float* __restrict__ x,
                                              const float* __restrict__ W,
                                              float* __restrict__ part) {
  const int n = blockIdx.y, ch = blockIdx.x, t = threadIdx.x;
  const int b = t >> 1, dg = t & 1;  // thread owns (b, 8 d's)
  const float4* wp = (const float4*)(W + ((size_t)(n * NC + ch * CPC)) * (ND * NI) + dg * (8 * NI));
  const float4* xp = (const float4*)(x + ((size_t)b * NC + ch * CPC) * NI);
  float acc[8] = {0, 0, 0, 0, 0, 0, 0, 0};
  for (int c = 0; c < CPC; ++c) {
    float4 x0 = xp[0], x1 = xp[1], x2 = xp[2], x3 = xp[3];
#pragma unroll
    for (int k = 0; k < 8; ++k) acc[k] = dot16(wp + k * 4, x0, x1, x2, x3, acc[k]);
    wp += (ND * NI) / 4;  // 256 floats per c
    xp += NI / 4;
  }
  float* pp = part + (((size_t)n * NCH + ch) * NB + b) * ND + dg * 8;
#pragma unroll
  for (int k = 0; k < 8; ++k) pp[k] = acc[k];
}

// Pass 1b: reduce chunks -> usum[b][n][d]
__global__ __launch_bounds__(256) void k_usum_reduce(const float* __restrict__ part,
                                                     float* __restrict__ usum) {
  const int id = blockIdx.x * 256 + threadIdx.x;  // 32768 = b*256 + n*16 + d
  const int b = id >> 8, nd = id & 255;
  const int n = nd >> 4, d = nd & 15;
  float s = 0.f;
#pragma unroll
  for (int ch = 0; ch < NCH; ++ch) s += part[(((size_t)n * NCH + ch) * NB + b) * ND + d];
  usum[id] = s;
}

// Pass 2: scores[b][c][n] = COEF * sum_d usum[b,n,d] * u_hat[b,n,c,d]  (u_hat recomputed)
__global__ __launch_bounds__(256) void k_scores(const float* __restrict__ x,
                                                const float* __restrict__ W,
                                                const float* __restrict__ usum,
                                                float* __restrict__ scores) {
  const int n = blockIdx.y, ch = blockIdx.x, t = threadIdx.x;
  const int b = t >> 1, dg = t & 1;
  const float* up = usum + ((size_t)b * NN + n) * ND + dg * 8;
  float us[8];
#pragma unroll
  for (int k = 0; k < 8; ++k) us[k] = up[k];
  const float4* wp = (const float4*)(W + ((size_t)(n * NC + ch * CPC)) * (ND * NI) + dg * (8 * NI));
  const float4* xp = (const float4*)(x + ((size_t)b * NC + ch * CPC) * NI);
  float* sp = scores + ((size_t)b * NC + ch * CPC) * NN + n;
  for (int c = 0; c < CPC; ++c) {
    float4 x0 = xp[0], x1 = xp[1], x2 = xp[2], x3 = xp[3];
    float p = 0.f;
#pragma unroll
    for (int k = 0; k < 8; ++k) {
      float d = dot16(wp + k * 4, x0, x1, x2, x3, 0.f);
      p = fmaf(us[k], d, p);
    }
    p += __shfl_xor(p, 1);  // combine the two d-halves (lanes t, t^1 share b)
    if (dg == 0) sp[0] = COEF * p;
    sp += NN;
    wp += (ND * NI) / 4;
    xp += NI / 4;
  }
}

// Pass 2b: per (b,c): softmax stats over the 16 n values
__global__ __launch_bounds__(256) void k_softmax(const float* __restrict__ scores,
                                                 float* __restrict__ rm,
                                                 float* __restrict__ rl) {
  const int id = blockIdx.x * 256 + threadIdx.x;  // 131072 = b*NC + c
  const float4* sp = (const float4*)(scores + (size_t)id * NN);
  float4 s0 = sp[0], s1 = sp[1], s2 = sp[2], s3 = sp[3];
  float v[16] = {s0.x, s0.y, s0.z, s0.w, s1.x, s1.y, s1.z, s1.w,
                 s2.x, s2.y, s2.z, s2.w, s3.x, s3.y, s3.z, s3.w};
  float m = v[0];
#pragma unroll
  for (int k = 1; k < 16; ++k) m = fmaxf(m, v[k]);
  float l = 0.f;
#pragma unroll
  for (int k = 0; k < 16; ++k) l += expf(v[k] - m);
  rm[id] = m;
  rl[id] = 1.0f / l;
}

// Pass 3: partial s over c-chunks. part[n][ch][b][d]; u_hat recomputed again
__global__ __launch_bounds__(256) void k_spart(const float* __restrict__ x,
                                               const float* __restrict__ W,
                                               const float* __restrict__ scores,
                                               const float* __restrict__ rm,
                                               const float* __restrict__ rl,
                                               const float* __restrict__ Bb,
                                               float* __restrict__ part) {
  const int n = blockIdx.y, ch = blockIdx.x, t = threadIdx.x;
  const int b = t >> 1, dg = t & 1;
  const float4* wp = (const float4*)(W + ((size_t)(n * NC + ch * CPC)) * (ND * NI) + dg * (8 * NI));
  const float4* xp = (const float4*)(x + ((size_t)b * NC + ch * CPC) * NI);
  const float* scp = scores + ((size_t)b * NC + ch * CPC) * NN + n;
  const float* rmp = rm + (size_t)b * NC + ch * CPC;
  const float* rlp = rl + (size_t)b * NC + ch * CPC;
  const float* bp = Bb + n * NC + ch * CPC;
  float acc[8] = {0, 0, 0, 0, 0, 0, 0, 0};
  for (int c = 0; c < CPC; ++c) {
    float coef = expf(scp[(size_t)c * NN] - rmp[c]) * rlp[c] + bp[c];
    float4 x0 = xp[0], x1 = xp[1], x2 = xp[2], x3 = xp[3];
#pragma unroll
    for (int k = 0; k < 8; ++k) {
      float d = dot16(wp + k * 4, x0, x1, x2, x3, 0.f);
      acc[k] = fmaf(coef, d, acc[k]);
    }
    wp += (ND * NI) / 4;
    xp += NI / 4;
  }
  float* pp = part + (((size_t)n * NCH + ch) * NB + b) * ND + dg * 8;
#pragma unroll
  for (int k = 0; k < 8; ++k) pp[k] = acc[k];
}

// Pass 4: reduce s over chunks + squash -> out[b][n][d]
__global__ __launch_bounds__(256) void k_squash(const float* __restrict__ part,
                                                float* __restrict__ out) {
  const int id = blockIdx.x * 256 + threadIdx.x;  // 2048 = b*NN + n
  const int b = id >> 4, n = id & 15;
  float sv[16] = {0, 0, 0, 0, 0, 0, 0, 0, 0, 0, 0, 0, 0, 0, 0, 0};
  for (int ch = 0; ch < NCH; ++ch) {
    const float4* pp = (const float4*)(part + (((size_t)n * NCH + ch) * NB + b) * ND);
    float4 p0 = pp[0], p1 = pp[1], p2 = pp[2], p3 = pp[3];
    sv[0] += p0.x; sv[1] += p0.y; sv[2] += p0.z; sv[3] += p0.w;
    sv[4] += p1.x; sv[5] += p1.y; sv[6] += p1.z; sv[7] += p1.w;
    sv[8] += p2.x; sv[9] += p2.y; sv[10] += p2.z; sv[11] += p2.w;
    sv[12] += p3.x; sv[13] += p3.y; sv[14] += p3.z; sv[15] += p3.w;
  }
  float sq = 0.f;
#pragma unroll
  for (int k = 0; k < 16; ++k) sq = fmaf(sv[k], sv[k], sq);
  float norm = sqrtf(sq);
  float scale = (1.0f - expf(-norm)) / sqrtf(sq + 1e-8f);
  float4* op = (float4*)(out + (size_t)id * 16);
  float4 o0 = {sv[0] * scale, sv[1] * scale, sv[2] * scale, sv[3] * scale};
  float4 o1 = {sv[4] * scale, sv[5] * scale, sv[6] * scale, sv[7] * scale};
  float4 o2 = {sv[8] * scale, sv[9] * scale, sv[10] * scale, sv[11] * scale};
  float4 o3 = {sv[12] * scale, sv[13] * scale, sv[14] * scale, sv[15] * scale};
  op[0] = o0; op[1] = o1; op[2] = o2; op[3] = o3;
}

extern "C" void kernel_launch(void* const* d_in, const int* in_sizes, int n_in,
                              void* d_out, int out_size, void* d_ws, size_t ws_size,
                              hipStream_t stream) {
  const float* x = (const float*)d_in[0];   // [128][1024][16]
  const float* W = (const float*)d_in[1];   // [1][16][1024][16][16]
  const float* Bb = (const float*)d_in[2];  // [16][1][1024]
  float* out = (float*)d_out;               // [128][16][16]
  float* ws = (float*)d_ws;

  // ws layout (floats). Total 3,440,640 f = 13.76 MB.
  float* part = ws;                       // [16][32][128][16] = 1,048,576 (reused for s-partials)
  float* usum = part + 1048576;           // 32,768
  float* scores = usum + 32768;           // [128][1024][16] = 2,097,152
  float* rm = scores + 2097152;           // 131,072
  float* rl = rm + 131072;                // 131,072

  dim3 g(NCH, NN);
  hipLaunchKernelGGL(k_usum, g, dim3(256), 0, stream, x, W, part);
  hipLaunchKernelGGL(k_usum_reduce, dim3(128), dim3(256), 0, stream, part, usum);
  hipLaunchKernelGGL(k_scores, g, dim3(256), 0, stream, x, W, usum, scores);
  hipLaunchKernelGGL(k_softmax, dim3(512), dim3(256), 0, stream, scores, rm, rl);
  hipLaunchKernelGGL(k_spart, g, dim3(256), 0, stream, x, W, scores, rm, rl, Bb, part);
  hipLaunchKernelGGL(k_squash, dim3(8), dim3(256), 0, stream, part, out);
}

// Round 2
// 79.968 us; speedup vs baseline: 5.4533x; 5.4533x over previous
//
#include <hip/hip_runtime.h>
#include <math.h>

// DigitCaps2: B=128, C=1024 in_caps, I=16 in_dim, N=16 num_caps, D=16 dim_caps
#define NB 128
#define NC 1024
#define NN 16
#define ND 16
#define NI 16
#define COEF 0.25f

typedef __attribute__((ext_vector_type(8))) short short8;
typedef __attribute__((ext_vector_type(4))) float f32x4;
typedef unsigned short ushort_t;

__device__ __forceinline__ unsigned short f2bf(float f) {
  unsigned int u = __builtin_bit_cast(unsigned int, f);
  u += 0x7fffu + ((u >> 16) & 1u);
  return (unsigned short)(u >> 16);
}
__device__ __forceinline__ float bf2f(unsigned short u) {
  unsigned int v = ((unsigned int)u) << 16;
  return __builtin_bit_cast(float, v);
}

// f32 -> bf16 convert, 8 elements per thread
__global__ __launch_bounds__(256) void k_cvt(const float4* __restrict__ src,
                                             ushort_t* __restrict__ dst, int n8) {
  int id = blockIdx.x * 256 + threadIdx.x;
  if (id >= n8) return;
  float4 a = src[2 * id], b = src[2 * id + 1];
  short8 o;
  o[0] = (short)f2bf(a.x); o[1] = (short)f2bf(a.y);
  o[2] = (short)f2bf(a.z); o[3] = (short)f2bf(a.w);
  o[4] = (short)f2bf(b.x); o[5] = (short)f2bf(b.y);
  o[6] = (short)f2bf(b.z); o[7] = (short)f2bf(b.w);
  *(short8*)(dst + (size_t)id * 8) = o;
}

// Pass A: usumT partials. wave = (n, bt, kc), kc in [0,32): 32 c's, 16 K=32 steps.
// D[d][b16] = sum_{c,i} W[n,c,d,i] * x[b,c,i]
__global__ __launch_bounds__(256) void k_passA(const ushort_t* __restrict__ xb,
                                               const ushort_t* __restrict__ Wb,
                                               float* __restrict__ part) {
  int wid = blockIdx.x * 4 + (threadIdx.x >> 6);  // 4096 waves
  int l = threadIdx.x & 63;
  int kc = wid & 31, bt = (wid >> 5) & 7, n = wid >> 8;
  int q = l >> 4, b16 = l & 15;
  int c0 = kc * 32;
  const ushort_t* ap = Wb + (((size_t)(n * NC + c0 + (q >> 1)) * ND + b16) * NI) + (q & 1) * 8;
  const ushort_t* bp = xb + (size_t)(bt * 16 + b16) * (NC * NI) + (c0 + (q >> 1)) * NI + (q & 1) * 8;
  f32x4 acc = {0.f, 0.f, 0.f, 0.f};
#pragma unroll
  for (int s = 0; s < 16; ++s) {
    short8 av = *(const short8*)ap;
    short8 bv = *(const short8*)bp;
    acc = __builtin_amdgcn_mfma_f32_16x16x32_bf16(av, bv, acc, 0, 0, 0);
    ap += 2 * ND * NI;
    bp += 2 * NI;
  }
  // part[n][bt][kc][b16][d] with lane rows d = q*4+r
  *(f32x4*)(part + ((size_t)((n * 8 + bt) * 32 + kc)) * 256 + b16 * 16 + q * 4) = acc;
}

// reduce partials -> usum[n][b][d]
__global__ __launch_bounds__(256) void k_reduceA(const float* __restrict__ part,
                                                 float* __restrict__ usum) {
  int id = blockIdx.x * 256 + threadIdx.x;  // 8192 = n*512 + b*4 + dq
  int n = id >> 9, r = id & 511, b = r >> 2, dq = r & 3;
  float4 s = {0.f, 0.f, 0.f, 0.f};
  for (int kc = 0; kc < 32; ++kc) {
    float4 p = *(const float4*)(part + ((size_t)((n * 8 + (b >> 4)) * 32 + kc)) * 256 + (b & 15) * 16 + dq * 4);
    s.x += p.x; s.y += p.y; s.z += p.z; s.w += p.w;
  }
  *(float4*)(usum + ((size_t)(n * NB + b)) * ND + dq * 4) = s;
}

// Pass B: scores. wave = (n, bt, cc), cc in [0,32): 32 c's, one zero-padded K=32 MFMA per c.
// sc[n][c][b] = COEF * sum_d usum[b,n,d] * u_hat[b,n,c,d]
__global__ __launch_bounds__(256) void k_passB(const ushort_t* __restrict__ xb,
                                               const ushort_t* __restrict__ Wb,
                                               const float* __restrict__ usum,
                                               float* __restrict__ sc) {
  int wid = blockIdx.x * 4 + (threadIdx.x >> 6);  // 4096 waves
  int l = threadIdx.x & 63;
  int cc = wid & 31, bt = (wid >> 5) & 7, n = wid >> 8;
  int q = l >> 4, b16 = l & 15;
  int c0 = cc * 32;
  float4 us = *(const float4*)(usum + ((size_t)(n * NB + bt * 16 + b16)) * ND + q * 4);
  const ushort_t* ap = Wb + (((size_t)(n * NC + c0) * ND + b16) * NI) + (q & 1) * 8;
  const ushort_t* bp = xb + (size_t)(bt * 16 + b16) * (NC * NI) + c0 * NI + (q & 1) * 8;
  float* sp = sc + ((size_t)(n * NC + c0)) * NB + bt * 16;
#pragma unroll 8
  for (int c = 0; c < 32; ++c) {
    short8 av = {0, 0, 0, 0, 0, 0, 0, 0};
    short8 bv = {0, 0, 0, 0, 0, 0, 0, 0};
    if (q < 2) {
      av = *(const short8*)ap;
      bv = *(const short8*)bp;
    }
    f32x4 z = {0.f, 0.f, 0.f, 0.f};
    f32x4 d = __builtin_amdgcn_mfma_f32_16x16x32_bf16(av, bv, z, 0, 0, 0);
    float v = us.x * d[0] + us.y * d[1] + us.z * d[2] + us.w * d[3];
    v += __shfl_xor(v, 16);
    v += __shfl_xor(v, 32);
    if (l < 16) sp[l] = COEF * v;
    ap += ND * NI;
    bp += NI;
    sp += NB;
  }
}

// softmax over n per (b,c), + bias; in-place on sc -> coef[n][c][b]
__global__ __launch_bounds__(256) void k_coef(float* __restrict__ sc,
                                              const float* __restrict__ Bb) {
  int id = blockIdx.x * 256 + threadIdx.x;  // 131072 = c*128 + b
  int c = id >> 7, b = id & 127;
  float v[NN];
  float m = -1e30f;
#pragma unroll
  for (int n = 0; n < NN; ++n) {
    v[n] = sc[((size_t)(n * NC + c)) * NB + b];
    m = fmaxf(m, v[n]);
  }
  float sum = 0.f;
#pragma unroll
  for (int n = 0; n < NN; ++n) {
    v[n] = expf(v[n] - m);
    sum += v[n];
  }
  float inv = 1.0f / sum;
#pragma unroll
  for (int n = 0; n < NN; ++n) {
    sc[((size_t)(n * NC + c)) * NB + b] = v[n] * inv + Bb[n * NC + c];
  }
}

// Pass C: s partials. Like pass A but B-frag scaled by coef[b,c] (from sc).
__global__ __launch_bounds__(256) void k_passC(const ushort_t* __restrict__ xb,
                                               const ushort_t* __restrict__ Wb,
                                               const float* __restrict__ sc,
                                               float* __restrict__ part) {
  int wid = blockIdx.x * 4 + (threadIdx.x >> 6);  // 4096 waves
  int l = threadIdx.x & 63;
  int kc = wid & 31, bt = (wid >> 5) & 7, n = wid >> 8;
  int q = l >> 4, b16 = l & 15;
  int c0 = kc * 32;
  const ushort_t* ap = Wb + (((size_t)(n * NC + c0 + (q >> 1)) * ND + b16) * NI) + (q & 1) * 8;
  const ushort_t* bp = xb + (size_t)(bt * 16 + b16) * (NC * NI) + (c0 + (q >> 1)) * NI + (q & 1) * 8;
  const float* cp = sc + ((size_t)(n * NC + c0 + (q >> 1))) * NB + bt * 16 + b16;
  f32x4 acc = {0.f, 0.f, 0.f, 0.f};
#pragma unroll
  for (int s = 0; s < 16; ++s) {
    short8 av = *(const short8*)ap;
    short8 xv = *(const short8*)bp;
    float cf = *cp;
    short8 bv;
#pragma unroll
    for (int j = 0; j < 8; ++j) {
      float xf = bf2f((unsigned short)xv[j]);
      bv[j] = (short)f2bf(xf * cf);
    }
    acc = __builtin_amdgcn_mfma_f32_16x16x32_bf16(av, bv, acc, 0, 0, 0);
    ap += 2 * ND * NI;
    bp += 2 * NI;
    cp += 2 * NB;
  }
  *(f32x4*)(part + ((size_t)((n * 8 + bt) * 32 + kc)) * 256 + b16 * 16 + q * 4) = acc;
}

// reduce s partials + squash -> out[b][n][d]
__global__ __launch_bounds__(256) void k_finish(const float* __restrict__ part,
                                                float* __restrict__ out) {
  int id = blockIdx.x * 256 + threadIdx.x;  // 2048 = b*16 + n
  int b = id >> 4, n = id & 15;
  float sv[16] = {0};
  for (int kc = 0; kc < 32; ++kc) {
    const float4* pp = (const float4*)(part + ((size_t)((n * 8 + (b >> 4)) * 32 + kc)) * 256 + (b & 15) * 16);
    float4 p0 = pp[0], p1 = pp[1], p2 = pp[2], p3 = pp[3];
    sv[0] += p0.x; sv[1] += p0.y; sv[2] += p0.z; sv[3] += p0.w;
    sv[4] += p1.x; sv[5] += p1.y; sv[6] += p1.z; sv[7] += p1.w;
    sv[8] += p2.x; sv[9] += p2.y; sv[10] += p2.z; sv[11] += p2.w;
    sv[12] += p3.x; sv[13] += p3.y; sv[14] += p3.z; sv[15] += p3.w;
  }
  float sq = 0.f;
#pragma unroll
  for (int k = 0; k < 16; ++k) sq = fmaf(sv[k], sv[k], sq);
  float norm = sqrtf(sq);
  float scale = (1.0f - expf(-norm)) / sqrtf(sq + 1e-8f);
  float4* op = (float4*)(out + (size_t)id * 16);
  float4 o0 = {sv[0] * scale, sv[1] * scale, sv[2] * scale, sv[3] * scale};
  float4 o1 = {sv[4] * scale, sv[5] * scale, sv[6] * scale, sv[7] * scale};
  float4 o2 = {sv[8] * scale, sv[9] * scale, sv[10] * scale, sv[11] * scale};
  float4 o3 = {sv[12] * scale, sv[13] * scale, sv[14] * scale, sv[15] * scale};
  op[0] = o0; op[1] = o1; op[2] = o2; op[3] = o3;
}

extern "C" void kernel_launch(void* const* d_in, const int* in_sizes, int n_in,
                              void* d_out, int out_size, void* d_ws, size_t ws_size,
                              hipStream_t stream) {
  const float* x = (const float*)d_in[0];   // [128][1024][16]
  const float* W = (const float*)d_in[1];   // [1][16][1024][16][16]
  const float* Bb = (const float*)d_in[2];  // [16][1][1024]
  float* out = (float*)d_out;               // [128][16][16]
  float* ws = (float*)d_ws;

  // ws layout (float units). Total 6,324,224 f = 25.3 MB.
  ushort_t* xb = (ushort_t*)ws;             // 2,097,152 bf16 = 1,048,576 f
  ushort_t* Wb = (ushort_t*)(ws + 1048576); // 4,194,304 bf16 = 2,097,152 f
  float* sc = ws + 1048576 + 2097152;       // [16][1024][128] = 2,097,152 f
  float* usum = sc + 2097152;               // [16][128][16] = 32,768 f
  float* part = usum + 32768;               // [16][8][32][16][16] = 1,048,576 f

  hipLaunchKernelGGL(k_cvt, dim3(1024), dim3(256), 0, stream, (const float4*)x, xb, 262144);
  hipLaunchKernelGGL(k_cvt, dim3(2048), dim3(256), 0, stream, (const float4*)W, Wb, 524288);
  hipLaunchKernelGGL(k_passA, dim3(1024), dim3(256), 0, stream, xb, Wb, part);
  hipLaunchKernelGGL(k_reduceA, dim3(32), dim3(256), 0, stream, part, usum);
  hipLaunchKernelGGL(k_passB, dim3(1024), dim3(256), 0, stream, xb, Wb, usum, sc);
  hipLaunchKernelGGL(k_coef, dim3(512), dim3(256), 0, stream, sc, Bb);
  hipLaunchKernelGGL(k_passC, dim3(1024), dim3(256), 0, stream, xb, Wb, sc, part);
  hipLaunchKernelGGL(k_finish, dim3(8), dim3(256), 0, stream, part, out);
}